// Round 5
// baseline (1066.091 us; speedup 1.0000x reference)
//
#include <hip/hip_runtime.h>
#include <math.h>

#define Hdim 4096
#define Vdim 32000
#define MTOK 2048
#define NKT 128            /* 4096/32 K-tiles */
#define TILEB 16384        /* one operand K-tile: 256 rows x 32 bf16 = 16 KB */
#define NSTRIPS 125        /* 32000/256 */
#define NMT 8              /* 2048/256 */

#define IGNORE_INDEX (-100)
#define BETA 0.1f
#define ALPHA 1.0f
#define SIMPO_GAMMA 0.5f
#define LABEL_SMOOTHING 0.0f

#define WT_BYTES ((size_t)NSTRIPS * NKT * TILEB)  /* 262,144,000 */
#define XT_BYTES ((size_t)NMT * NKT * TILEB)      /*  16,777,216 */

typedef __attribute__((ext_vector_type(8))) short bf16x8;
typedef __attribute__((ext_vector_type(4))) float f32x4;

static __device__ __forceinline__ short f2bf(float f) {
    unsigned int u = __float_as_uint(f);
    u = u + 0x7fffu + ((u >> 16) & 1u);   // RNE
    return (short)(u >> 16);
}

static __device__ __forceinline__ f32x4 vmax4(f32x4 a, f32x4 b) {
    f32x4 r;
    r[0] = fmaxf(a[0], b[0]); r[1] = fmaxf(a[1], b[1]);
    r[2] = fmaxf(a[2], b[2]); r[3] = fmaxf(a[3], b[3]);
    return r;
}

static __device__ __forceinline__ void gload_lds16(const void* g, void* l) {
    __builtin_amdgcn_global_load_lds(
        (const __attribute__((address_space(1))) unsigned int*)g,
        (__attribute__((address_space(3))) unsigned int*)l,
        16, 0, 0);
}

// ---------------------------------------------------------------------------
// Conversions: f32 -> bf16 K-tiles (256 rows x 32 bf16), dest-indexed.
// Within a tile, row's octet kb stored at slot = kb ^ ((row>>1)&3)  (XOR
// involution; GEMM reads with the same formula -> conflict-free ds_read_b128).
// ---------------------------------------------------------------------------
__global__ void k_convW(const float* __restrict__ W, char* __restrict__ Wt)
{
    const unsigned int gc = blockIdx.x * 256 + threadIdx.x;   // dest octet, < 16,384,000
    const unsigned int tile = gc >> 10;        // 16 KB tiles: (vt*128 + kt)
    const unsigned int o = gc & 1023u;
    const unsigned int row = o >> 2, slot = o & 3u;
    const unsigned int kb = slot ^ ((row >> 1) & 3u);
    const unsigned int vt = tile >> 7, kt = tile & 127u;
    const float* src = W + (size_t)(vt * 256 + row) * Hdim + (kt * 4 + kb) * 8;
    float4 a0 = *(const float4*)(src);
    float4 a1 = *(const float4*)(src + 4);
    bf16x8 v;
    v[0] = f2bf(a0.x); v[1] = f2bf(a0.y); v[2] = f2bf(a0.z); v[3] = f2bf(a0.w);
    v[4] = f2bf(a1.x); v[5] = f2bf(a1.y); v[6] = f2bf(a1.z); v[7] = f2bf(a1.w);
    *reinterpret_cast<bf16x8*>(Wt + (size_t)tile * TILEB + o * 16) = v;
}

__global__ void k_convX(const float* __restrict__ x, char* __restrict__ Xt)
{
    const unsigned int gc = blockIdx.x * 256 + threadIdx.x;   // < 1,048,576
    const unsigned int tile = gc >> 10;        // (mt*128 + kt)
    const unsigned int o = gc & 1023u;
    const unsigned int row = o >> 2, slot = o & 3u;
    const unsigned int kb = slot ^ ((row >> 1) & 3u);
    const unsigned int mt = tile >> 7, kt = tile & 127u;
    const float* src = x + (size_t)(mt * 256 + row) * Hdim + (kt * 4 + kb) * 8;
    float4 a0 = *(const float4*)(src);
    float4 a1 = *(const float4*)(src + 4);
    bf16x8 v;
    v[0] = f2bf(a0.x); v[1] = f2bf(a0.y); v[2] = f2bf(a0.z); v[3] = f2bf(a0.w);
    v[4] = f2bf(a1.x); v[5] = f2bf(a1.y); v[6] = f2bf(a1.z); v[7] = f2bf(a1.w);
    *reinterpret_cast<bf16x8*>(Xt + (size_t)tile * TILEB + o * 16) = v;
}

// ---------------------------------------------------------------------------
// 256x256 deep-pipelined GEMM + per-strip online-softmax partials.
// 8 waves (2 row x 4 col), per-wave 128x64 output. BK=32, 4-slot LDS ring.
// Prefetch DISTANCE 3 (T4: vmcnt(6) = 2 loads/half-tile x 3 half-tiles in
// flight); fragment ds_reads pipelined one phase ahead; setprio around MFMA.
// ---------------------------------------------------------------------------
__global__ __launch_bounds__(512, 2)
void k_gemm8(const char* __restrict__ Wt, const char* __restrict__ Xt,
             const int* __restrict__ y,
             float* __restrict__ pmax, float* __restrict__ psum,
             float* __restrict__ tgt)
{
    const int bid = blockIdx.x;
    // XCD-bijective swizzle: 1000 blocks = 8 XCDs x 125; vt-major chunks.
    const int orig = (bid & 7) * 125 + (bid >> 3);
    const int vt = orig >> 3;          // 0..124
    const int mt = orig & 7;           // 0..7
    const int m0 = mt * 256, v0 = vt * 256;
    const int tid = threadIdx.x, lane = tid & 63, wid = tid >> 6;
    const int wr = wid >> 2;           // 0..1  (row half)
    const int wc = wid & 3;            // 0..3  (col quarter)

    __shared__ char ring[4][2][TILEB];        // 128 KB: [slot][A|B][16KB]
    __shared__ float wredM[2][4][128];
    __shared__ float wredS[2][4][128];
    __shared__ int yloc[256];

    if (tid < 256) yloc[tid] = y[m0 + tid];

    f32x4 acc[8][4];
#pragma unroll
    for (int i = 0; i < 8; i++)
#pragma unroll
        for (int j = 0; j < 4; j++) acc[i][j] = (f32x4)(0.0f);

    const char* xsrc = Xt + (size_t)mt * (NKT * TILEB);
    const char* wsrc = Wt + (size_t)vt * (NKT * TILEB);

    // Per-lane swizzled LDS byte offsets (layout verified by refcheck).
    int offA[2][4], offB[4];
#pragma unroll
    for (int rh = 0; rh < 2; rh++)
#pragma unroll
        for (int rf = 0; rf < 4; rf++) {
            const int row = wr * 128 + rh * 64 + rf * 16 + (lane & 15);
            offA[rh][rf] = row * 64 + (((lane >> 4) ^ ((row >> 1) & 3)) << 4);
        }
#pragma unroll
    for (int cf = 0; cf < 4; cf++) {
        const int row = wc * 64 + cf * 16 + (lane & 15);
        offB[cf] = row * 64 + (((lane >> 4) ^ ((row >> 1) & 3)) << 4);
    }

#define STAGE(tt, h) do {                                                   \
        const char* _s = ((h) ? wsrc : xsrc) + (size_t)(tt) * TILEB;        \
        char* _d = &ring[(tt) & 3][(h)][0];                                 \
        const int _o = wid * 1024;                                          \
        gload_lds16(_s + _o + lane * 16,        _d + _o);                   \
        gload_lds16(_s + 8192 + _o + lane * 16, _d + 8192 + _o);            \
    } while (0)

    // Prologue: stage tiles 0,1,2 (12 loads); wait tile 0 -> vmcnt(8); barrier.
    STAGE(0, 0); STAGE(0, 1); STAGE(1, 0); STAGE(1, 1); STAGE(2, 0); STAGE(2, 1);
    asm volatile("s_waitcnt vmcnt(8)" ::: "memory");
    asm volatile("s_waitcnt lgkmcnt(0)" ::: "memory");   // yloc visibility
    __builtin_amdgcn_s_barrier();
    asm volatile("" ::: "memory");

    // Pre-load frags for tile 0 phase 0 (A rows-half0 + all B cols).
    bf16x8 a0[4], b0[4], a1[4], a0n[4], b0n[4];
    {
        const char* As = &ring[0][0][0];
        const char* Bs = &ring[0][1][0];
#pragma unroll
        for (int rf = 0; rf < 4; rf++) a0[rf] = *(const bf16x8*)(As + offA[0][rf]);
#pragma unroll
        for (int cf = 0; cf < 4; cf++) b0[cf] = *(const bf16x8*)(Bs + offB[cf]);
        asm volatile("" ::: "memory");
    }

#pragma unroll 1
    for (int t = 0; t < NKT; ++t) {
        const char* As = &ring[t & 3][0][0];

        // ---- phase 0: stage A of t+3; pre-read a1 (this tile, rows-half1);
        //      MFMA on a0/b0 (read last phase); counted vmcnt; barrier.
        if (t < NKT - 3) STAGE(t + 3, 0);
#pragma unroll
        for (int rf = 0; rf < 4; rf++) a1[rf] = *(const bf16x8*)(As + offA[1][rf]);
        asm volatile("" ::: "memory");
        __builtin_amdgcn_s_setprio(1);
#pragma unroll
        for (int rf = 0; rf < 4; rf++)
#pragma unroll
            for (int cf = 0; cf < 4; cf++)
                acc[rf][cf] = __builtin_amdgcn_mfma_f32_16x16x32_bf16(a0[rf], b0[cf], acc[rf][cf], 0, 0, 0);
        __builtin_amdgcn_s_setprio(0);
        // Guarantee tile t+1 fully resident; keep 3 half-tiles (6 loads) in flight.
        if (t <= NKT - 4)      { asm volatile("s_waitcnt vmcnt(6)" ::: "memory"); }
        else if (t == NKT - 3) { asm volatile("s_waitcnt vmcnt(4)" ::: "memory"); }
        else                   { asm volatile("s_waitcnt vmcnt(0)" ::: "memory"); }
        __builtin_amdgcn_s_barrier();
        asm volatile("" ::: "memory");

        // ---- phase 1: stage B of t+3; pre-read next tile's a0/b0 frags
        //      (residency proven by phase-0 vmcnt+barrier); MFMA on a1/b0.
        if (t < NKT - 3) STAGE(t + 3, 1);
        if (t < NKT - 1) {
            const char* An = &ring[(t + 1) & 3][0][0];
            const char* Bn = &ring[(t + 1) & 3][1][0];
#pragma unroll
            for (int rf = 0; rf < 4; rf++) a0n[rf] = *(const bf16x8*)(An + offA[0][rf]);
#pragma unroll
            for (int cf = 0; cf < 4; cf++) b0n[cf] = *(const bf16x8*)(Bn + offB[cf]);
        }
        asm volatile("" ::: "memory");
        __builtin_amdgcn_s_setprio(1);
#pragma unroll
        for (int rf = 0; rf < 4; rf++)
#pragma unroll
            for (int cf = 0; cf < 4; cf++)
                acc[4 + rf][cf] = __builtin_amdgcn_mfma_f32_16x16x32_bf16(a1[rf], b0[cf], acc[4 + rf][cf], 0, 0, 0);
        __builtin_amdgcn_s_setprio(0);
        __builtin_amdgcn_s_barrier();
        asm volatile("" ::: "memory");

#pragma unroll
        for (int rf = 0; rf < 4; rf++) a0[rf] = a0n[rf];
#pragma unroll
        for (int cf = 0; cf < 4; cf++) b0[cf] = b0n[cf];
    }
#undef STAGE

    // ---- target-logit extraction (C layout m89: col=lane&15, row=(lane>>4)*4+r)
    {
        const int colbase = v0 + wc * 64 + (lane & 15);
        const int rbase = wr * 128 + ((lane >> 4) << 2);
#pragma unroll
        for (int i = 0; i < 8; i++) {
#pragma unroll
            for (int r = 0; r < 4; r++) {
                const int rloc = rbase + i * 16 + r;
                const int yv = yloc[rloc];
#pragma unroll
                for (int j = 0; j < 4; j++)
                    if (yv == colbase + j * 16) tgt[m0 + rloc] = acc[i][j][r];
            }
        }
    }

    // ---- per-row max / sum(exp) over wave's 64 cols
#pragma unroll
    for (int i = 0; i < 8; i++) {
        f32x4 rm = acc[i][0];
#pragma unroll
        for (int j = 1; j < 4; j++) rm = vmax4(rm, acc[i][j]);
#pragma unroll
        for (int off = 1; off < 16; off <<= 1) {
            f32x4 o;
#pragma unroll
            for (int r = 0; r < 4; r++) o[r] = __shfl_xor(rm[r], off);
            rm = vmax4(rm, o);
        }
        f32x4 s = (f32x4)(0.0f);
#pragma unroll
        for (int j = 0; j < 4; j++)
#pragma unroll
            for (int r = 0; r < 4; r++) s[r] += expf(acc[i][j][r] - rm[r]);
#pragma unroll
        for (int off = 1; off < 16; off <<= 1) {
#pragma unroll
            for (int r = 0; r < 4; r++) s[r] += __shfl_xor(s[r], off);
        }
        if ((lane & 15) == 0) {
            const int rl = i * 16 + ((lane >> 4) << 2);
#pragma unroll
            for (int r = 0; r < 4; r++) {
                wredM[wr][wc][rl + r] = rm[r];
                wredS[wr][wc][rl + r] = s[r];
            }
        }
    }
    __syncthreads();
    if (tid < 256) {
        const int wr2 = tid >> 7, rl = tid & 127;
        float M = wredM[wr2][0][rl];
#pragma unroll
        for (int c = 1; c < 4; c++) M = fmaxf(M, wredM[wr2][c][rl]);
        float S = 0.0f;
#pragma unroll
        for (int c = 0; c < 4; c++) S += wredS[wr2][c][rl] * expf(wredM[wr2][c][rl] - M);
        pmax[(size_t)vt * MTOK + m0 + tid] = M;
        psum[(size_t)vt * MTOK + m0 + tid] = S;
    }
}

// ---------------------------------------------------------------------------
__global__ void k_finalize(const float* __restrict__ pmax, const float* __restrict__ psum,
                           const float* __restrict__ tgt, float* __restrict__ logp,
                           int nstrips)
{
    const int m = blockIdx.x * blockDim.x + threadIdx.x;
    if (m >= MTOK) return;
    float M = -INFINITY;
    for (int s = 0; s < nstrips; s++) M = fmaxf(M, pmax[(size_t)s * MTOK + m]);
    float S = 0.0f;
    for (int s = 0; s < nstrips; s++)
        S += psum[(size_t)s * MTOK + m] * expf(pmax[(size_t)s * MTOK + m] - M);
    logp[m] = tgt[m] - (M + logf(S));
}

static __device__ __forceinline__ float logsig(float z) {
    return (z >= 0.0f) ? -log1pf(expf(-z)) : (z - log1pf(expf(z)));
}

__global__ void k_loss(const float* __restrict__ logp, const int* __restrict__ y,
                       float* __restrict__ out)
{
    const int tid = threadIdx.x;
    __shared__ float sbv[4], sbc[4];
    __shared__ float seqsum[8], seqcnt[8];

    for (int s = 0; s < 8; s++) {
        const int m = s * 256 + tid;
        const int msk = (y[m] != IGNORE_INDEX) ? 1 : 0;
        float vv = msk ? logp[m] : 0.0f;
        float cc = (float)msk;
#pragma unroll
        for (int o = 32; o > 0; o >>= 1) {
            vv += __shfl_down(vv, o);
            cc += __shfl_down(cc, o);
        }
        if ((tid & 63) == 0) { sbv[tid >> 6] = vv; sbc[tid >> 6] = cc; }
        __syncthreads();
        if (tid == 0) {
            float a = 0, b = 0;
            for (int w = 0; w < 4; w++) { a += sbv[w]; b += sbc[w]; }
            seqsum[s] = a; seqcnt[s] = b;
        }
        __syncthreads();
    }
    if (tid == 0) {
        float avg[8];
        for (int s = 0; s < 8; s++) avg[s] = seqsum[s] / seqcnt[s];
        float nsum = 0, ncnt = 0;
        for (int s = 0; s < 4; s++) { nsum += seqsum[s]; ncnt += seqcnt[s]; }
        const float nll = -nsum / ncnt;
        float lsum = 0;
        for (int i = 0; i < 4; i++) {
            const float d = avg[i] - avg[i + 4] - SIMPO_GAMMA / BETA;
            const float z = BETA * d;
            lsum += logsig(z) * (1.0f - LABEL_SMOOTHING) + logsig(-z) * LABEL_SMOOTHING;
        }
        out[0] = nll * ALPHA - lsum * 0.25f;
    }
}

// ---------------------------------------------------------------------------
// Fallback GEMM (in-loop conversion, 128x128 tiles, 250 strips) — only used
// if ws_size is too small for the bf16 workspace.
// ---------------------------------------------------------------------------
__global__ __launch_bounds__(256, 2)
void k_gemm_lse_fb(const float* __restrict__ x, const float* __restrict__ W,
                   const int* __restrict__ y,
                   float* __restrict__ pmax, float* __restrict__ psum,
                   float* __restrict__ tgt)
{
    const int bid = blockIdx.x;
    const int mt = bid & 15;
    const int vt = bid >> 4;
    const int m0 = mt * 128;
    const int v0 = vt * 128;
    const int tid = threadIdx.x;
    const int lane = tid & 63;
    const int wid = tid >> 6;
    const int wm = (wid >> 1) * 64;
    const int wv = (wid & 1) * 64;

    __shared__ short lsA[128 * 64];
    __shared__ short lsB[128 * 64];
    __shared__ int   yloc[128];
    __shared__ float wredM[4][64];
    __shared__ float wredS[4][64];

    if (tid < 128) yloc[tid] = y[m0 + tid];

    f32x4 acc[4][4];
#pragma unroll
    for (int i = 0; i < 4; i++)
#pragma unroll
        for (int j = 0; j < 4; j++) acc[i][j] = (f32x4)(0.0f);

    const int srow = tid >> 3;
    const int skb  = tid & 7;
    const float* xg = x + (size_t)m0 * Hdim;
    const float* wg = W + (size_t)v0 * Hdim;

#pragma unroll 1
    for (int kt = 0; kt < Hdim / 64; ++kt) {
        const int k0 = kt * 64;
        __syncthreads();
#pragma unroll
        for (int t = 0; t < 4; t++) {
            const int row  = t * 32 + srow;
            const int slot = skb ^ (row & 7);
            const float* pa = xg + (size_t)row * Hdim + k0 + skb * 8;
            const float* pb = wg + (size_t)row * Hdim + k0 + skb * 8;
            float4 a0 = *(const float4*)(pa);
            float4 a1 = *(const float4*)(pa + 4);
            float4 b0 = *(const float4*)(pb);
            float4 b1 = *(const float4*)(pb + 4);
            bf16x8 va, vb;
            va[0] = f2bf(a0.x); va[1] = f2bf(a0.y); va[2] = f2bf(a0.z); va[3] = f2bf(a0.w);
            va[4] = f2bf(a1.x); va[5] = f2bf(a1.y); va[6] = f2bf(a1.z); va[7] = f2bf(a1.w);
            vb[0] = f2bf(b0.x); vb[1] = f2bf(b0.y); vb[2] = f2bf(b0.z); vb[3] = f2bf(b0.w);
            vb[4] = f2bf(b1.x); vb[5] = f2bf(b1.y); vb[6] = f2bf(b1.z); vb[7] = f2bf(b1.w);
            *reinterpret_cast<bf16x8*>(&lsA[row * 64 + slot * 8]) = va;
            *reinterpret_cast<bf16x8*>(&lsB[row * 64 + slot * 8]) = vb;
        }
        __syncthreads();
#pragma unroll
        for (int ks = 0; ks < 2; ++ks) {
            bf16x8 af[4], bfr[4];
            const int kb = ks * 4 + (lane >> 4);
#pragma unroll
            for (int i = 0; i < 4; i++) {
                const int row = wm + i * 16 + (lane & 15);
                af[i] = *reinterpret_cast<const bf16x8*>(&lsA[row * 64 + (kb ^ (row & 7)) * 8]);
            }
#pragma unroll
            for (int j = 0; j < 4; j++) {
                const int row = wv + j * 16 + (lane & 15);
                bfr[j] = *reinterpret_cast<const bf16x8*>(&lsB[row * 64 + (kb ^ (row & 7)) * 8]);
            }
#pragma unroll
            for (int i = 0; i < 4; i++)
#pragma unroll
                for (int j = 0; j < 4; j++)
                    acc[i][j] = __builtin_amdgcn_mfma_f32_16x16x32_bf16(af[i], bfr[j], acc[i][j], 0, 0, 0);
        }
    }

    __syncthreads();
    {
        const int colbase = v0 + wv + (lane & 15);
        const int rbase = wm + ((lane >> 4) << 2);
#pragma unroll
        for (int i = 0; i < 4; i++) {
#pragma unroll
            for (int r = 0; r < 4; r++) {
                const int rloc = rbase + i * 16 + r;
                const int yv = yloc[rloc];
#pragma unroll
                for (int j = 0; j < 4; j++)
                    if (yv == colbase + j * 16) tgt[m0 + rloc] = acc[i][j][r];
            }
        }
    }
    f32x4 rm[4], rs[4];
#pragma unroll
    for (int i = 0; i < 4; i++) {
        rm[i] = acc[i][0];
#pragma unroll
        for (int j = 1; j < 4; j++) rm[i] = vmax4(rm[i], acc[i][j]);
#pragma unroll
        for (int off = 1; off < 16; off <<= 1) {
            f32x4 o;
#pragma unroll
            for (int r = 0; r < 4; r++) o[r] = __shfl_xor(rm[i][r], off);
            rm[i] = vmax4(rm[i], o);
        }
    }
#pragma unroll
    for (int i = 0; i < 4; i++) {
        f32x4 s = (f32x4)(0.0f);
#pragma unroll
        for (int j = 0; j < 4; j++)
#pragma unroll
            for (int r = 0; r < 4; r++) s[r] += expf(acc[i][j][r] - rm[i][r]);
#pragma unroll
        for (int off = 1; off < 16; off <<= 1) {
#pragma unroll
            for (int r = 0; r < 4; r++) s[r] += __shfl_xor(s[r], off);
        }
        rs[i] = s;
    }
    if ((lane & 15) == 0) {
        const int g = lane >> 4;
#pragma unroll
        for (int i = 0; i < 4; i++)
#pragma unroll
            for (int r = 0; r < 4; r++) {
                wredM[wid][i * 16 + g * 4 + r] = rm[i][r];
                wredS[wid][i * 16 + g * 4 + r] = rs[i][r];
            }
    }
    __syncthreads();
    if (tid < 128) {
        const int r = tid;
        const int g = r >> 6;
        const int rl = r & 63;
        const float ma = wredM[2 * g][rl],  mb = wredM[2 * g + 1][rl];
        const float sa = wredS[2 * g][rl],  sb = wredS[2 * g + 1][rl];
        const float M = fmaxf(ma, mb);
        const float S = sa * expf(ma - M) + sb * expf(mb - M);
        pmax[(size_t)vt * MTOK + m0 + r] = M;
        psum[(size_t)vt * MTOK + m0 + r] = S;
    }
}

// ---------------------------------------------------------------------------
extern "C" void kernel_launch(void* const* d_in, const int* in_sizes, int n_in,
                              void* d_out, int out_size, void* d_ws, size_t ws_size,
                              hipStream_t stream)
{
    const float* x = (const float*)d_in[0];
    const float* W = (const float*)d_in[1];
    const int*   y = (const int*)d_in[2];
    float* out = (float*)d_out;

    const size_t partials = (size_t)2 * NSTRIPS * MTOK * sizeof(float) + 2 * MTOK * sizeof(float);
    const size_t need = WT_BYTES + XT_BYTES + partials;

    if (ws_size >= need) {
        char* Wt = (char*)d_ws;
        char* Xt = Wt + WT_BYTES;
        float* pmax = (float*)(Xt + XT_BYTES);
        float* psum = pmax + (size_t)NSTRIPS * MTOK;
        float* tgt  = psum + (size_t)NSTRIPS * MTOK;
        float* logp = tgt + MTOK;
        k_convW<<<dim3(64000), dim3(256), 0, stream>>>(W, Wt);
        k_convX<<<dim3(4096), dim3(256), 0, stream>>>(x, Xt);
        k_gemm8<<<dim3(NSTRIPS * NMT), dim3(512), 0, stream>>>(Wt, Xt, y, pmax, psum, tgt);
        k_finalize<<<dim3(MTOK / 256), dim3(256), 0, stream>>>(pmax, psum, tgt, logp, NSTRIPS);
        k_loss<<<dim3(1), dim3(256), 0, stream>>>(logp, y, out);
    } else {
        float* pmax = (float*)d_ws;                       // 250 strips of 128
        float* psum = pmax + (size_t)250 * MTOK;
        float* tgt  = psum + (size_t)250 * MTOK;
        float* logp = tgt + MTOK;
        k_gemm_lse_fb<<<dim3(250 * 16), dim3(256), 0, stream>>>(x, W, y, pmax, psum, tgt);
        k_finalize<<<dim3(MTOK / 256), dim3(256), 0, stream>>>(pmax, psum, tgt, logp, 250);
        k_loss<<<dim3(1), dim3(256), 0, stream>>>(logp, y, out);
    }
}

// Round 6
// 795.699 us; speedup vs baseline: 1.3398x; 1.3398x over previous
//
#include <hip/hip_runtime.h>
#include <math.h>

#define Hdim 4096
#define Vdim 32000
#define MTOK 2048
#define NKT 128            /* 4096/32 K-tiles */
#define TILE8 8192         /* one operand K-tile: 128 rows x 32 bf16 = 8 KB */
#define NSTRIPS 250        /* 32000/128 */
#define NMT 16             /* 2048/128 */

#define IGNORE_INDEX (-100)
#define BETA 0.1f
#define ALPHA 1.0f
#define SIMPO_GAMMA 0.5f
#define LABEL_SMOOTHING 0.0f

#define WT_BYTES ((size_t)NSTRIPS * NKT * TILE8)  /* 262,144,000 */
#define XT_BYTES ((size_t)NMT * NKT * TILE8)      /*  16,777,216 */

typedef __attribute__((ext_vector_type(8))) short bf16x8;
typedef __attribute__((ext_vector_type(4))) float f32x4;

static __device__ __forceinline__ short f2bf(float f) {
    unsigned int u = __float_as_uint(f);
    u = u + 0x7fffu + ((u >> 16) & 1u);   // RNE
    return (short)(u >> 16);
}

static __device__ __forceinline__ f32x4 vmax4(f32x4 a, f32x4 b) {
    f32x4 r;
    r[0] = fmaxf(a[0], b[0]); r[1] = fmaxf(a[1], b[1]);
    r[2] = fmaxf(a[2], b[2]); r[3] = fmaxf(a[3], b[3]);
    return r;
}

static __device__ __forceinline__ void gload_lds16(const void* g, void* l) {
    __builtin_amdgcn_global_load_lds(
        (const __attribute__((address_space(1))) unsigned int*)g,
        (__attribute__((address_space(3))) unsigned int*)l,
        16, 0, 0);
}

// ---------------------------------------------------------------------------
// Conversions: f32 -> bf16 K-tiles (128 rows x 32 bf16 = 8 KB), dest-indexed.
// Row's K-octet kb stored at slot = kb ^ ((row>>1)&3) (XOR involution; GEMM
// reads with the same formula -> max 2-way LDS aliasing = free per m136).
// ---------------------------------------------------------------------------
__global__ void k_convW(const float* __restrict__ W, char* __restrict__ Wt)
{
    const unsigned int gc = blockIdx.x * 256 + threadIdx.x;   // dest octet, < 16,384,000
    const unsigned int tile = gc >> 9;         // 512 octets per tile: (vt*128 + kt)
    const unsigned int o = gc & 511u;
    const unsigned int row = o >> 2, slot = o & 3u;
    const unsigned int kb = slot ^ ((row >> 1) & 3u);
    const unsigned int vt = tile >> 7, kt = tile & 127u;
    const float* src = W + (size_t)(vt * 128 + row) * Hdim + kt * 32 + kb * 8;
    float4 a0 = *(const float4*)(src);
    float4 a1 = *(const float4*)(src + 4);
    bf16x8 v;
    v[0] = f2bf(a0.x); v[1] = f2bf(a0.y); v[2] = f2bf(a0.z); v[3] = f2bf(a0.w);
    v[4] = f2bf(a1.x); v[5] = f2bf(a1.y); v[6] = f2bf(a1.z); v[7] = f2bf(a1.w);
    *reinterpret_cast<bf16x8*>(Wt + (size_t)tile * TILE8 + o * 16) = v;
}

__global__ void k_convX(const float* __restrict__ x, char* __restrict__ Xt)
{
    const unsigned int gc = blockIdx.x * 256 + threadIdx.x;   // < 1,048,576
    const unsigned int tile = gc >> 9;         // (mt*128 + kt)
    const unsigned int o = gc & 511u;
    const unsigned int row = o >> 2, slot = o & 3u;
    const unsigned int kb = slot ^ ((row >> 1) & 3u);
    const unsigned int mt = tile >> 7, kt = tile & 127u;
    const float* src = x + (size_t)(mt * 128 + row) * Hdim + kt * 32 + kb * 8;
    float4 a0 = *(const float4*)(src);
    float4 a1 = *(const float4*)(src + 4);
    bf16x8 v;
    v[0] = f2bf(a0.x); v[1] = f2bf(a0.y); v[2] = f2bf(a0.z); v[3] = f2bf(a0.w);
    v[4] = f2bf(a1.x); v[5] = f2bf(a1.y); v[6] = f2bf(a1.z); v[7] = f2bf(a1.w);
    *reinterpret_cast<bf16x8*>(Xt + (size_t)tile * TILE8 + o * 16) = v;
}

// ---------------------------------------------------------------------------
// m97/m103-structure GEMM (measured 912 TF in learn_hip at this exact shape):
// 128x128 tile, BK=32, SINGLE 16 KB+16 KB LDS buffer, 4 waves, plain
// 2-barrier loop, global_load_lds w16, ~3 blocks/CU for implicit TLP.
// Fused epilogue: per-strip online-softmax partials + target-logit extract.
// ---------------------------------------------------------------------------
__global__ __launch_bounds__(256, 3)
void k_gemm97(const char* __restrict__ Wt, const char* __restrict__ Xt,
              const int* __restrict__ y,
              float* __restrict__ pmax, float* __restrict__ psum,
              float* __restrict__ tgt)
{
    const int bid = blockIdx.x;
    // XCD-bijective swizzle: 4000 blocks = 8 XCDs x 500; vt-major chunks so
    // the 16 blocks sharing a W strip are consecutive on one XCD (L2 reuse).
    const int orig = (bid & 7) * 500 + (bid >> 3);
    const int vt = orig >> 4;          // 0..249
    const int mt = orig & 15;          // 0..15
    const int m0 = mt * 128, v0 = vt * 128;
    const int tid = threadIdx.x, lane = tid & 63, wid = tid >> 6;
    const int wm = (wid >> 1) * 64;    // wave row offset
    const int wv = (wid & 1) * 64;     // wave col offset

    __shared__ char lsA[TILE8];
    __shared__ char lsB[TILE8];
    __shared__ int   yloc[128];
    __shared__ float wredM[4][64];
    __shared__ float wredS[4][64];

    if (tid < 128) yloc[tid] = y[m0 + tid];

    f32x4 acc[4][4];
#pragma unroll
    for (int i = 0; i < 4; i++)
#pragma unroll
        for (int j = 0; j < 4; j++) acc[i][j] = (f32x4)(0.0f);

    const char* gA = Xt + ((size_t)mt * NKT) * TILE8;
    const char* gB = Wt + ((size_t)vt * NKT) * TILE8;

    // Per-lane swizzled LDS byte offsets (layout = conv's involution).
    const int kb = lane >> 4;
    int offA[4], offB[4];
#pragma unroll
    for (int rf = 0; rf < 4; rf++) {
        const int row = wm + rf * 16 + (lane & 15);
        offA[rf] = row * 64 + ((kb ^ ((row >> 1) & 3)) << 4);
    }
#pragma unroll
    for (int cf = 0; cf < 4; cf++) {
        const int row = wv + cf * 16 + (lane & 15);
        offB[cf] = row * 64 + ((kb ^ ((row >> 1) & 3)) << 4);
    }

#pragma unroll 1
    for (int kt = 0; kt < NKT; ++kt) {
        __syncthreads();   // prior iteration's LDS reads complete before overwrite
        const char* sA = gA + (size_t)kt * TILE8;
        const char* sB = gB + (size_t)kt * TILE8;
        gload_lds16(sA + tid * 16,        lsA + tid * 16);
        gload_lds16(sA + 4096 + tid * 16, lsA + 4096 + tid * 16);
        gload_lds16(sB + tid * 16,        lsB + tid * 16);
        gload_lds16(sB + 4096 + tid * 16, lsB + 4096 + tid * 16);
        __syncthreads();   // drains vmcnt: tile resident (TLP across 3 blocks hides)

        bf16x8 af[4], bf[4];
#pragma unroll
        for (int rf = 0; rf < 4; rf++) af[rf] = *(const bf16x8*)(lsA + offA[rf]);
#pragma unroll
        for (int cf = 0; cf < 4; cf++) bf[cf] = *(const bf16x8*)(lsB + offB[cf]);
#pragma unroll
        for (int rf = 0; rf < 4; rf++)
#pragma unroll
            for (int cf = 0; cf < 4; cf++)
                acc[rf][cf] = __builtin_amdgcn_mfma_f32_16x16x32_bf16(af[rf], bf[cf], acc[rf][cf], 0, 0, 0);
    }

    __syncthreads();

    // ---- target-logit extraction (C layout m89: col=lane&15, row=(lane>>4)*4+r)
    {
        const int colbase = v0 + wv + (lane & 15);
        const int rbase = wm + ((lane >> 4) << 2);
#pragma unroll
        for (int i = 0; i < 4; i++) {
#pragma unroll
            for (int r = 0; r < 4; r++) {
                const int rloc = rbase + i * 16 + r;
                const int yv = yloc[rloc];
#pragma unroll
                for (int j = 0; j < 4; j++)
                    if (yv == colbase + j * 16) tgt[m0 + rloc] = acc[i][j][r];
            }
        }
    }

    // ---- per-row max / sum(exp) over this wave's 64 cols
    f32x4 rm[4], rs[4];
#pragma unroll
    for (int i = 0; i < 4; i++) {
        rm[i] = acc[i][0];
#pragma unroll
        for (int j = 1; j < 4; j++) rm[i] = vmax4(rm[i], acc[i][j]);
#pragma unroll
        for (int off = 1; off < 16; off <<= 1) {
            f32x4 o;
#pragma unroll
            for (int r = 0; r < 4; r++) o[r] = __shfl_xor(rm[i][r], off);
            rm[i] = vmax4(rm[i], o);
        }
    }
#pragma unroll
    for (int i = 0; i < 4; i++) {
        f32x4 s = (f32x4)(0.0f);
#pragma unroll
        for (int j = 0; j < 4; j++)
#pragma unroll
            for (int r = 0; r < 4; r++) s[r] += expf(acc[i][j][r] - rm[i][r]);
#pragma unroll
        for (int off = 1; off < 16; off <<= 1) {
#pragma unroll
            for (int r = 0; r < 4; r++) s[r] += __shfl_xor(s[r], off);
        }
        rs[i] = s;
    }
    if ((lane & 15) == 0) {
        const int g = lane >> 4;
#pragma unroll
        for (int i = 0; i < 4; i++)
#pragma unroll
            for (int r = 0; r < 4; r++) {
                wredM[wid][i * 16 + g * 4 + r] = rm[i][r];
                wredS[wid][i * 16 + g * 4 + r] = rs[i][r];
            }
    }
    __syncthreads();
    if (tid < 128) {
        const int r = tid;
        const int g = r >> 6;          // row-half -> wave pair (2g, 2g+1)
        const int rl = r & 63;
        const float ma = wredM[2 * g][rl],  mb = wredM[2 * g + 1][rl];
        const float sa = wredS[2 * g][rl],  sb = wredS[2 * g + 1][rl];
        const float M = fmaxf(ma, mb);
        const float S = sa * expf(ma - M) + sb * expf(mb - M);
        pmax[(size_t)vt * MTOK + m0 + r] = M;
        psum[(size_t)vt * MTOK + m0 + r] = S;
    }
}

// ---------------------------------------------------------------------------
__global__ void k_finalize(const float* __restrict__ pmax, const float* __restrict__ psum,
                           const float* __restrict__ tgt, float* __restrict__ logp,
                           int nstrips)
{
    const int m = blockIdx.x * blockDim.x + threadIdx.x;
    if (m >= MTOK) return;
    float M = -INFINITY;
    for (int s = 0; s < nstrips; s++) M = fmaxf(M, pmax[(size_t)s * MTOK + m]);
    float S = 0.0f;
    for (int s = 0; s < nstrips; s++)
        S += psum[(size_t)s * MTOK + m] * expf(pmax[(size_t)s * MTOK + m] - M);
    logp[m] = tgt[m] - (M + logf(S));
}

static __device__ __forceinline__ float logsig(float z) {
    return (z >= 0.0f) ? -log1pf(expf(-z)) : (z - log1pf(expf(z)));
}

__global__ void k_loss(const float* __restrict__ logp, const int* __restrict__ y,
                       float* __restrict__ out)
{
    const int tid = threadIdx.x;
    __shared__ float sbv[4], sbc[4];
    __shared__ float seqsum[8], seqcnt[8];

    for (int s = 0; s < 8; s++) {
        const int m = s * 256 + tid;
        const int msk = (y[m] != IGNORE_INDEX) ? 1 : 0;
        float vv = msk ? logp[m] : 0.0f;
        float cc = (float)msk;
#pragma unroll
        for (int o = 32; o > 0; o >>= 1) {
            vv += __shfl_down(vv, o);
            cc += __shfl_down(cc, o);
        }
        if ((tid & 63) == 0) { sbv[tid >> 6] = vv; sbc[tid >> 6] = cc; }
        __syncthreads();
        if (tid == 0) {
            float a = 0, b = 0;
            for (int w = 0; w < 4; w++) { a += sbv[w]; b += sbc[w]; }
            seqsum[s] = a; seqcnt[s] = b;
        }
        __syncthreads();
    }
    if (tid == 0) {
        float avg[8];
        for (int s = 0; s < 8; s++) avg[s] = seqsum[s] / seqcnt[s];
        float nsum = 0, ncnt = 0;
        for (int s = 0; s < 4; s++) { nsum += seqsum[s]; ncnt += seqcnt[s]; }
        const float nll = -nsum / ncnt;
        float lsum = 0;
        for (int i = 0; i < 4; i++) {
            const float d = avg[i] - avg[i + 4] - SIMPO_GAMMA / BETA;
            const float z = BETA * d;
            lsum += logsig(z) * (1.0f - LABEL_SMOOTHING) + logsig(-z) * LABEL_SMOOTHING;
        }
        out[0] = nll * ALPHA - lsum * 0.25f;
    }
}

// ---------------------------------------------------------------------------
// Fallback GEMM (in-loop conversion, 128x128 tiles) — only if ws too small.
// ---------------------------------------------------------------------------
__global__ __launch_bounds__(256, 2)
void k_gemm_lse_fb(const float* __restrict__ x, const float* __restrict__ W,
                   const int* __restrict__ y,
                   float* __restrict__ pmax, float* __restrict__ psum,
                   float* __restrict__ tgt)
{
    const int bid = blockIdx.x;
    const int mt = bid & 15;
    const int vt = bid >> 4;
    const int m0 = mt * 128;
    const int v0 = vt * 128;
    const int tid = threadIdx.x;
    const int lane = tid & 63;
    const int wid = tid >> 6;
    const int wm = (wid >> 1) * 64;
    const int wv = (wid & 1) * 64;

    __shared__ short lsA[128 * 64];
    __shared__ short lsB[128 * 64];
    __shared__ int   yloc[128];
    __shared__ float wredM[4][64];
    __shared__ float wredS[4][64];

    if (tid < 128) yloc[tid] = y[m0 + tid];

    f32x4 acc[4][4];
#pragma unroll
    for (int i = 0; i < 4; i++)
#pragma unroll
        for (int j = 0; j < 4; j++) acc[i][j] = (f32x4)(0.0f);

    const int srow = tid >> 3;
    const int skb  = tid & 7;
    const float* xg = x + (size_t)m0 * Hdim;
    const float* wg = W + (size_t)v0 * Hdim;

#pragma unroll 1
    for (int kt = 0; kt < Hdim / 64; ++kt) {
        const int k0 = kt * 64;
        __syncthreads();
#pragma unroll
        for (int t = 0; t < 4; t++) {
            const int row  = t * 32 + srow;
            const int slot = skb ^ (row & 7);
            const float* pa = xg + (size_t)row * Hdim + k0 + skb * 8;
            const float* pb = wg + (size_t)row * Hdim + k0 + skb * 8;
            float4 a0 = *(const float4*)(pa);
            float4 a1 = *(const float4*)(pa + 4);
            float4 b0 = *(const float4*)(pb);
            float4 b1 = *(const float4*)(pb + 4);
            bf16x8 va, vb;
            va[0] = f2bf(a0.x); va[1] = f2bf(a0.y); va[2] = f2bf(a0.z); va[3] = f2bf(a0.w);
            va[4] = f2bf(a1.x); va[5] = f2bf(a1.y); va[6] = f2bf(a1.z); va[7] = f2bf(a1.w);
            vb[0] = f2bf(b0.x); vb[1] = f2bf(b0.y); vb[2] = f2bf(b0.z); vb[3] = f2bf(b0.w);
            vb[4] = f2bf(b1.x); vb[5] = f2bf(b1.y); vb[6] = f2bf(b1.z); vb[7] = f2bf(b1.w);
            *reinterpret_cast<bf16x8*>(&lsA[row * 64 + slot * 8]) = va;
            *reinterpret_cast<bf16x8*>(&lsB[row * 64 + slot * 8]) = vb;
        }
        __syncthreads();
#pragma unroll
        for (int ks = 0; ks < 2; ++ks) {
            bf16x8 af[4], bfr[4];
            const int kb2 = ks * 4 + (lane >> 4);
#pragma unroll
            for (int i = 0; i < 4; i++) {
                const int row = wm + i * 16 + (lane & 15);
                af[i] = *reinterpret_cast<const bf16x8*>(&lsA[row * 64 + (kb2 ^ (row & 7)) * 8]);
            }
#pragma unroll
            for (int j = 0; j < 4; j++) {
                const int row = wv + j * 16 + (lane & 15);
                bfr[j] = *reinterpret_cast<const bf16x8*>(&lsB[row * 64 + (kb2 ^ (row & 7)) * 8]);
            }
#pragma unroll
            for (int i = 0; i < 4; i++)
#pragma unroll
                for (int j = 0; j < 4; j++)
                    acc[i][j] = __builtin_amdgcn_mfma_f32_16x16x32_bf16(af[i], bfr[j], acc[i][j], 0, 0, 0);
        }
    }

    __syncthreads();
    {
        const int colbase = v0 + wv + (lane & 15);
        const int rbase = wm + ((lane >> 4) << 2);
#pragma unroll
        for (int i = 0; i < 4; i++) {
#pragma unroll
            for (int r = 0; r < 4; r++) {
                const int rloc = rbase + i * 16 + r;
                const int yv = yloc[rloc];
#pragma unroll
                for (int j = 0; j < 4; j++)
                    if (yv == colbase + j * 16) tgt[m0 + rloc] = acc[i][j][r];
            }
        }
    }
    f32x4 rm[4], rs[4];
#pragma unroll
    for (int i = 0; i < 4; i++) {
        rm[i] = acc[i][0];
#pragma unroll
        for (int j = 1; j < 4; j++) rm[i] = vmax4(rm[i], acc[i][j]);
#pragma unroll
        for (int off = 1; off < 16; off <<= 1) {
            f32x4 o;
#pragma unroll
            for (int r = 0; r < 4; r++) o[r] = __shfl_xor(rm[i][r], off);
            rm[i] = vmax4(rm[i], o);
        }
    }
#pragma unroll
    for (int i = 0; i < 4; i++) {
        f32x4 s = (f32x4)(0.0f);
#pragma unroll
        for (int j = 0; j < 4; j++)
#pragma unroll
            for (int r = 0; r < 4; r++) s[r] += expf(acc[i][j][r] - rm[i][r]);
#pragma unroll
        for (int off = 1; off < 16; off <<= 1) {
#pragma unroll
            for (int r = 0; r < 4; r++) s[r] += __shfl_xor(s[r], off);
        }
        rs[i] = s;
    }
    if ((lane & 15) == 0) {
        const int g = lane >> 4;
#pragma unroll
        for (int i = 0; i < 4; i++)
#pragma unroll
            for (int r = 0; r < 4; r++) {
                wredM[wid][i * 16 + g * 4 + r] = rm[i][r];
                wredS[wid][i * 16 + g * 4 + r] = rs[i][r];
            }
    }
    __syncthreads();
    if (tid < 128) {
        const int r = tid;
        const int g = r >> 6;
        const int rl = r & 63;
        const float ma = wredM[2 * g][rl],  mb = wredM[2 * g + 1][rl];
        const float sa = wredS[2 * g][rl],  sb = wredS[2 * g + 1][rl];
        const float M = fmaxf(ma, mb);
        const float S = sa * expf(ma - M) + sb * expf(mb - M);
        pmax[(size_t)vt * MTOK + m0 + r] = M;
        psum[(size_t)vt * MTOK + m0 + r] = S;
    }
}

// ---------------------------------------------------------------------------
extern "C" void kernel_launch(void* const* d_in, const int* in_sizes, int n_in,
                              void* d_out, int out_size, void* d_ws, size_t ws_size,
                              hipStream_t stream)
{
    const float* x = (const float*)d_in[0];
    const float* W = (const float*)d_in[1];
    const int*   y = (const int*)d_in[2];
    float* out = (float*)d_out;

    const size_t partials = (size_t)2 * NSTRIPS * MTOK * sizeof(float) + 2 * MTOK * sizeof(float);
    const size_t need = WT_BYTES + XT_BYTES + partials;

    if (ws_size >= need) {
        char* Wt = (char*)d_ws;
        char* Xt = Wt + WT_BYTES;
        float* pmax = (float*)(Xt + XT_BYTES);
        float* psum = pmax + (size_t)NSTRIPS * MTOK;
        float* tgt  = psum + (size_t)NSTRIPS * MTOK;
        float* logp = tgt + MTOK;
        k_convW<<<dim3(64000), dim3(256), 0, stream>>>(W, Wt);
        k_convX<<<dim3(4096), dim3(256), 0, stream>>>(x, Xt);
        k_gemm97<<<dim3(NSTRIPS * NMT), dim3(256), 0, stream>>>(Wt, Xt, y, pmax, psum, tgt);
        k_finalize<<<dim3(MTOK / 256), dim3(256), 0, stream>>>(pmax, psum, tgt, logp, NSTRIPS);
        k_loss<<<dim3(1), dim3(256), 0, stream>>>(logp, y, out);
    } else {
        float* pmax = (float*)d_ws;
        float* psum = pmax + (size_t)NSTRIPS * MTOK;
        float* tgt  = psum + (size_t)NSTRIPS * MTOK;
        float* logp = tgt + MTOK;
        k_gemm_lse_fb<<<dim3(NSTRIPS * NMT), dim3(256), 0, stream>>>(x, W, y, pmax, psum, tgt);
        k_finalize<<<dim3(MTOK / 256), dim3(256), 0, stream>>>(pmax, psum, tgt, logp, NSTRIPS);
        k_loss<<<dim3(1), dim3(256), 0, stream>>>(logp, y, out);
    }
}